// Round 12
// baseline (4028.264 us; speedup 1.0000x reference)
//
#include <hip/hip_runtime.h>
#include <hip/hip_fp16.h>

// Bidirectional 2-layer LSTM: B=32, T=1024, IN=256, H=256.
// ws layout: xg  f16 [2][32][1024][1024]        = 134,217,728 B
//            hbt u64 [2][32][2 parity][256 j]   =     262,144 B  (tagged h)
// total = 134,479,872 B
//
// Tag protocol (per layer, base B): producer at step st stores (B+st+1, h) into
// parity st&1; consumer at step st polls parity (st+1)&1 for tag B+st.
// L0 base=1, L1 base=4096; hbt memset to 0 each launch (replay-safe).
//
// recur11 = r11 topology (4-wg same-XCD groups, 192 one-slot pollers, W in 64
// half2 VGPRs, 54KB occupancy pad) with the post-dot pipeline collapsed into
// the wave:
//   lane t = cell*8 + q*2 + kh  ->  kh partner = t^1, gate partners = t^2/4/6
//   kh-sum: quad_perm(1,0,3,2) DPP; gate gather: quad_perm(2,3,0,1) + ds_swizzle
//   xor4 + quad_perm(2,3,0,1). Every lane updates its cell redundantly; lanes
//   t%8==0 store h (tagged + outp + local stage) right after the dots.
// Deletes scr, barrier #2, and the serialized wave-0 epilogue; tagged store
// moves ~400cy earlier, directly shortening the peers' poll wait.
// ONE barrier/step safety (parity-dbuf stage): pollers/producers write buffer
// (st+1)&1 only after passing barrier(st); every thread's reads of that buffer
// (during compute st-1) completed before it arrived at barrier(st) (the
// compiler drains all cnts before s_barrier). Disjoint slots: pollers write
// foreign 192, producers own 64.

#define T_LEN 1024
#define BATCH 32
#define HID   256
#define G4    1024

struct __align__(8) Half4 { __half x, y, z, w; };

typedef _Float16 f16x2 __attribute__((ext_vector_type(2)));

__device__ __forceinline__ f16x2 pack_f16x2(float lo, float hi) {
    f16x2 r; r.x = (_Float16)lo; r.y = (_Float16)hi; return r;
}
__device__ __forceinline__ float dot2acc(f16x2 a, f16x2 b, float c) {
#if __has_builtin(__builtin_amdgcn_fdot2)
    return __builtin_amdgcn_fdot2(a, b, c, false);
#else
    return c + (float)a.x * (float)b.x + (float)a.y * (float)b.y;
#endif
}

template <int CTRL>
__device__ __forceinline__ float qperm(float v) {
    int i = __builtin_bit_cast(int, v);
    int r = __builtin_amdgcn_update_dpp(i, i, CTRL, 0xF, 0xF, true);
    return __builtin_bit_cast(float, r);
}
__device__ __forceinline__ float swz_xor4(float v) {
    int i = __builtin_bit_cast(int, v);
    int r = __builtin_amdgcn_ds_swizzle(i, 0x101F);   // xor 4, and 0x1F
    return __builtin_bit_cast(float, r);
}

__device__ __forceinline__ float sigm(float x) { return 1.0f / (1.0f + __expf(-x)); }
__device__ __forceinline__ float tanh_fast(float x) {
    float e = __expf(2.f * x);            // inf-safe
    return 1.f - 2.f / (e + 1.f);
}

// ---- projection: xg[dir][m][n] = sum_k A[m][k]*W[n][k] + bih[n] + bhh[n], stored f16 ----
__global__ __launch_bounds__(256) void proj_kernel(
    const float* __restrict__ A, int K,
    const float* __restrict__ Wf, const float* __restrict__ Wr,
    const float* __restrict__ bih_f, const float* __restrict__ bhh_f,
    const float* __restrict__ bih_r, const float* __restrict__ bhh_r,
    __half* __restrict__ xg)
{
    const int dir = blockIdx.z;
    const float* __restrict__ W   = dir ? Wr    : Wf;
    const float* __restrict__ bih = dir ? bih_r : bih_f;
    const float* __restrict__ bhh = dir ? bhh_r : bhh_f;
    __half* __restrict__ outp = xg + (size_t)dir * ((size_t)BATCH * T_LEN * G4);

    __shared__ float As[32][132];
    __shared__ float Bs[32][132];

    const int tid = threadIdx.x;
    const int tx  = tid & 15;
    const int ty  = tid >> 4;
    const int tx4 = tx * 4;
    const int ty4 = ty * 4;
    const int m0  = blockIdx.y * 128;
    const int n0  = blockIdx.x * 128;

    float acc[8][8];
    #pragma unroll
    for (int i = 0; i < 8; ++i)
        #pragma unroll
        for (int j = 0; j < 8; ++j) acc[i][j] = 0.f;

    for (int k0 = 0; k0 < K; k0 += 32) {
        #pragma unroll
        for (int it = 0; it < 4; ++it) {
            int f   = tid + it * 256;
            int row = f >> 3;
            int c4  = (f & 7) * 4;
            float4 av = *reinterpret_cast<const float4*>(&A[(size_t)(m0 + row) * K + k0 + c4]);
            float4 bv = *reinterpret_cast<const float4*>(&W[(size_t)(n0 + row) * K + k0 + c4]);
            As[c4 + 0][row] = av.x; As[c4 + 1][row] = av.y;
            As[c4 + 2][row] = av.z; As[c4 + 3][row] = av.w;
            Bs[c4 + 0][row] = bv.x; Bs[c4 + 1][row] = bv.y;
            Bs[c4 + 2][row] = bv.z; Bs[c4 + 3][row] = bv.w;
        }
        __syncthreads();
        #pragma unroll
        for (int k = 0; k < 32; ++k) {
            float4 a0 = *reinterpret_cast<const float4*>(&As[k][ty4]);
            float4 a1 = *reinterpret_cast<const float4*>(&As[k][64 + ty4]);
            float4 b0 = *reinterpret_cast<const float4*>(&Bs[k][tx4]);
            float4 b1 = *reinterpret_cast<const float4*>(&Bs[k][64 + tx4]);
            float a[8] = {a0.x,a0.y,a0.z,a0.w,a1.x,a1.y,a1.z,a1.w};
            float b[8] = {b0.x,b0.y,b0.z,b0.w,b1.x,b1.y,b1.z,b1.w};
            #pragma unroll
            for (int i = 0; i < 8; ++i)
                #pragma unroll
                for (int j = 0; j < 8; ++j)
                    acc[i][j] = fmaf(a[i], b[j], acc[i][j]);
        }
        __syncthreads();
    }

    float bb[8];
    #pragma unroll
    for (int j = 0; j < 8; ++j) {
        int n = n0 + ((j < 4) ? (tx4 + j) : (64 + tx4 + (j - 4)));
        bb[j] = bih[n] + bhh[n];
    }
    #pragma unroll
    for (int i = 0; i < 8; ++i) {
        int m = m0 + ((i < 4) ? (ty4 + i) : (64 + ty4 + (i - 4)));
        Half4 v0, v1;
        v0.x = __float2half(acc[i][0] + bb[0]);
        v0.y = __float2half(acc[i][1] + bb[1]);
        v0.z = __float2half(acc[i][2] + bb[2]);
        v0.w = __float2half(acc[i][3] + bb[3]);
        v1.x = __float2half(acc[i][4] + bb[4]);
        v1.y = __float2half(acc[i][5] + bb[5]);
        v1.z = __float2half(acc[i][6] + bb[6]);
        v1.w = __float2half(acc[i][7] + bb[7]);
        *reinterpret_cast<Half4*>(&outp[(size_t)m * G4 + n0 + tx4])      = v0;
        *reinterpret_cast<Half4*>(&outp[(size_t)m * G4 + n0 + 64 + tx4]) = v1;
    }
}

// ---- cooperative recurrence: in-wave epilogue, 1 barrier/step ----
// bid = jq*64 + (d*32 + b). Group = 4 jq of one (d,b), same bid%8 -> same XCD.
// thread t: cell = t>>3 (0..63), q = (t>>1)&3, kh = t&1.
// Gate row n = q*256 + jq*64 + cell; W = n's k-half = 128 fp16 = 64 VGPRs.
// Pollers: t<256, slot t, skip own quarter (t>>6==jq) -> 192 active.
// Producers: t%8==0 (q=0,kh=0) -> cell's h.
extern "C" __global__ __launch_bounds__(512, 2) void recur11_kernel(
    const __half* __restrict__ xg,
    const float* __restrict__ Whh_f,           // [1024][256]
    const float* __restrict__ Whh_r,
    float* __restrict__ outp,                  // [32][1024][512]
    unsigned long long* __restrict__ hbt,      // [2][32][2][256] tagged
    unsigned int tagbase)
{
    // 54 KB static LDS (1 KB used): caps occupancy at 2 blocks/CU at compile
    // time -> allocator budget 128 VGPRs -> no spill (r11-proven trick).
    __shared__ char smem[55296];
    __half* stage = (__half*)smem;             // [2 parity][256 j]

    const int tid = threadIdx.x;
    const int bid = blockIdx.x;
    const int jq  = bid >> 6;
    const int d   = (bid >> 5) & 1;
    const int b   = bid & 31;
    const float* __restrict__ Whh = d ? Whh_r : Whh_f;

    const int cell = tid >> 3;                 // 0..63
    const int q    = (tid >> 1) & 3;           // gate i/f/g/o
    const int kh   = tid & 1;                  // k-half
    const int n_my = (q << 8) + jq * 64 + cell;

    // --- one-time: 128 fp16 weights (row n_my, k-half kh) = 64 half2 VGPRs ---
    unsigned wh[64];
    {
        const float* wrow = Whh + (size_t)n_my * HID + kh * 128;
        #pragma unroll
        for (int i = 0; i < 32; ++i) {
            float4 w4 = *reinterpret_cast<const float4*>(&wrow[i * 4]);
            wh[2 * i]     = __builtin_bit_cast(unsigned, pack_f16x2(w4.x, w4.y));
            wh[2 * i + 1] = __builtin_bit_cast(unsigned, pack_f16x2(w4.z, w4.w));
        }
    }
    #pragma unroll
    for (int i = 0; i < 64; ++i) asm volatile("" : "+v"(wh[i]));   // no remat

    unsigned long long* hb = hbt + (size_t)(d * 32 + b) * 512;   // [parity][256]

    // init: h[-1]=0 -> global tag parity 1 (peers) + local stage[0] own quarter
    if (tid < 64) {
        __hip_atomic_store(&hb[256 + jq * 64 + tid],
                           (unsigned long long)tagbase << 32,
                           __ATOMIC_RELAXED, __HIP_MEMORY_SCOPE_AGENT);
        stage[0 * 256 + jq * 64 + tid] = __float2half(0.f);
    }

    // poller role: t<256, slot t, skip own quarter -> 192 active
    const bool isPoll = (tid < 256) && ((tid >> 6) != jq);

    // xg: kh==0 lanes add xg(b, n_my)
    const __half* __restrict__ xgp =
        xg + ((size_t)(d * BATCH + b)) * T_LEN * G4 + n_my;

    float c_state = 0.f;                 // redundant over the cell's 8 lanes

    for (int st = 0; st < T_LEN; ++st) {
        const int t = d ? (T_LEN - 1 - st) : st;

        // prefetch xg (independent of h) before polling
        float xv = (kh == 0) ? __half2float(xgp[(size_t)t * G4]) : 0.f;

        __half* scur = stage + (st & 1) * 256;

        // stage foreign quarters (parity (st+1)&1, tag tagbase+st)
        if (isPoll) {
            const unsigned int exp = tagbase + (unsigned)st;
            unsigned long long* src = hb + (size_t)((st + 1) & 1) * 256 + tid;
            unsigned long long v =
                __hip_atomic_load(src, __ATOMIC_RELAXED, __HIP_MEMORY_SCOPE_AGENT);
            while ((unsigned int)(v >> 32) != exp)
                v = __hip_atomic_load(src, __ATOMIC_RELAXED, __HIP_MEMORY_SCOPE_AGENT);
            scur[tid] = __float2half(__uint_as_float((unsigned int)v));
        }
        __syncthreads();   // stage[st&1] complete (own quarter from step st-1)

        // 128-k dot: W in 64 half2 VGPRs, h via 2-addr broadcast ds_read_b128
        float a0 = xv, a1 = 0.f;
        {
            const float4* hp = reinterpret_cast<const float4*>(scur + kh * 128);
            #pragma unroll
            for (int i = 0; i < 16; ++i) {
                float4 hv = hp[i];
                a0 = dot2acc(__builtin_bit_cast(f16x2, hv.x), __builtin_bit_cast(f16x2, wh[4 * i + 0]), a0);
                a1 = dot2acc(__builtin_bit_cast(f16x2, hv.y), __builtin_bit_cast(f16x2, wh[4 * i + 1]), a1);
                a0 = dot2acc(__builtin_bit_cast(f16x2, hv.z), __builtin_bit_cast(f16x2, wh[4 * i + 2]), a0);
                a1 = dot2acc(__builtin_bit_cast(f16x2, hv.w), __builtin_bit_cast(f16x2, wh[4 * i + 3]), a1);
            }
        }
        float v = a0 + a1;
        v += qperm<0xB1>(v);               // xor1: kh-sum -> full gate value

        // gate gather: xor2 / xor4 / xor6 neighbors
        float x2 = qperm<0x4E>(v);
        float x4 = swz_xor4(v);
        float x6 = qperm<0x4E>(x4);

        float gi = (q == 0) ? v  : (q == 1) ? x2 : (q == 2) ? x4 : x6;
        float gf = (q == 0) ? x2 : (q == 1) ? v  : (q == 2) ? x6 : x4;
        float gg = (q == 0) ? x4 : (q == 1) ? x6 : (q == 2) ? v  : x2;
        float go = (q == 0) ? x6 : (q == 1) ? x4 : (q == 2) ? x2 : v;

        float ii = sigm(gi);
        float ff = sigm(gf);
        float g2 = tanh_fast(gg);
        float oo = sigm(go);
        c_state = ff * c_state + ii * g2;
        float h = oo * tanh_fast(c_state);

        if ((tid & 7) == 0) {   // producer: cell's h
            const int j = jq * 64 + cell;
            // local fast path (read at st+1 from stage[(st+1)&1])
            stage[((st + 1) & 1) * 256 + j] = __float2half(h);
            // tagged store for the 3 peers (issued ~100cy after the dots)
            unsigned long long pv =
                ((unsigned long long)(tagbase + (unsigned)st + 1u) << 32) | __float_as_uint(h);
            __hip_atomic_store(&hb[(size_t)(st & 1) * 256 + j], pv,
                               __ATOMIC_RELAXED, __HIP_MEMORY_SCOPE_AGENT);
            outp[((size_t)b * T_LEN + t) * (2 * HID) + d * HID + j] = h;
        }
        // single barrier per step: next iteration's barrier orders everything
        // (see safety note in header).
    }
}

extern "C" void kernel_launch(void* const* d_in, const int* in_sizes, int n_in,
                              void* d_out, int out_size, void* d_ws, size_t ws_size,
                              hipStream_t stream)
{
    const float* x       = (const float*)d_in[0];
    const float* W_ih_f0 = (const float*)d_in[1];
    const float* W_hh_f0 = (const float*)d_in[2];
    const float* b_ih_f0 = (const float*)d_in[3];
    const float* b_hh_f0 = (const float*)d_in[4];
    const float* W_ih_r0 = (const float*)d_in[5];
    const float* W_hh_r0 = (const float*)d_in[6];
    const float* b_ih_r0 = (const float*)d_in[7];
    const float* b_hh_r0 = (const float*)d_in[8];
    const float* W_ih_f1 = (const float*)d_in[9];
    const float* W_hh_f1 = (const float*)d_in[10];
    const float* b_ih_f1 = (const float*)d_in[11];
    const float* b_hh_f1 = (const float*)d_in[12];
    const float* W_ih_r1 = (const float*)d_in[13];
    const float* W_hh_r1 = (const float*)d_in[14];
    const float* b_ih_r1 = (const float*)d_in[15];
    const float* b_hh_r1 = (const float*)d_in[16];

    float* outp = (float*)d_out;

    __half* xg = (__half*)d_ws;
    const size_t xg_bytes = (size_t)2 * BATCH * T_LEN * G4 * sizeof(__half); // 134,217,728
    unsigned long long* hbt = (unsigned long long*)((char*)d_ws + xg_bytes); // 262,144 B

    // clean tag space every launch (no stale-tag pre-match, fully replay-safe)
    hipMemsetAsync(hbt, 0, 262144, stream);

    // ---- layer 0 ----
    proj_kernel<<<dim3(8, 256, 2), 256, 0, stream>>>(x, 256, W_ih_f0, W_ih_r0,
        b_ih_f0, b_hh_f0, b_ih_r0, b_hh_r0, xg);
    {
        const __half* xg_c = xg;
        unsigned int base0 = 1u;
        void* args[] = {(void*)&xg_c, (void*)&W_hh_f0, (void*)&W_hh_r0,
                        (void*)&outp, (void*)&hbt, (void*)&base0};
        hipLaunchCooperativeKernel(reinterpret_cast<const void*>(recur11_kernel),
                                   dim3(256), dim3(512), args, 0, stream);
    }

    // ---- layer 1 ----
    proj_kernel<<<dim3(8, 256, 2), 256, 0, stream>>>(outp, 512, W_ih_f1, W_ih_r1,
        b_ih_f1, b_hh_f1, b_ih_r1, b_hh_r1, xg);
    {
        const __half* xg_c = xg;
        unsigned int base1 = 4096u;
        void* args[] = {(void*)&xg_c, (void*)&W_hh_f1, (void*)&W_hh_r1,
                        (void*)&outp, (void*)&hbt, (void*)&base1};
        hipLaunchCooperativeKernel(reinterpret_cast<const void*>(recur11_kernel),
                                   dim3(256), dim3(512), args, 0, stream);
    }
}

// Round 13
// 2992.170 us; speedup vs baseline: 1.3463x; 1.3463x over previous
//
#include <hip/hip_runtime.h>
#include <hip/hip_fp16.h>

// Bidirectional 2-layer LSTM: B=32, T=1024, IN=256, H=256.
// ws layout: xg  f16 [2][32][1024][1024]        = 134,217,728 B
//            hbt u64 [2][32][2 parity][256 j]   =     262,144 B  (tagged h)
// total = 134,479,872 B
//
// Tag protocol (per layer, base B): producer at step st stores (B+st+1, h) into
// parity st&1; consumer at step st polls parity (st+1)&1 for tag B+st.
// L0 base=1, L1 base=4096; hbt memset to 0 each launch (replay-safe).
//
// r13 = r11's recur10 (best recurrence: 1.38ms, conflicts 0) + MFMA projection.
// r12 lesson: in-wave epilogue w/ ds_swizzle = 134M conflicts + 2x VALU -> revert.
// proj_mfma: fp16 MFMA 16x16x32, 128x128 tile, BK=64, f32->f16 staged LDS,
// f32 accumulate, bias in epilogue, coalesced f16 output via LDS C-tile.

#define T_LEN 1024
#define BATCH 32
#define HID   256
#define G4    1024

struct __align__(16) Half8 { __half h[8]; };

typedef _Float16 f16x2 __attribute__((ext_vector_type(2)));
typedef _Float16 half8_t __attribute__((ext_vector_type(8)));
typedef float f32x4 __attribute__((ext_vector_type(4)));

__device__ __forceinline__ f16x2 pack_f16x2(float lo, float hi) {
    f16x2 r; r.x = (_Float16)lo; r.y = (_Float16)hi; return r;
}
__device__ __forceinline__ float dot2acc(f16x2 a, f16x2 b, float c) {
#if __has_builtin(__builtin_amdgcn_fdot2)
    return __builtin_amdgcn_fdot2(a, b, c, false);
#else
    return c + (float)a.x * (float)b.x + (float)a.y * (float)b.y;
#endif
}

__device__ __forceinline__ float sigm(float x) { return 1.0f / (1.0f + __expf(-x)); }
__device__ __forceinline__ float tanh_fast(float x) {
    float e = __expf(2.f * x);            // inf-safe
    return 1.f - 2.f / (e + 1.f);
}

// ---- MFMA projection: xg[dir][m][n] = sum_k A[m][k]*W[n][k] + bih[n]+bhh[n] ----
// A f32 [32768,K] K-major; W f32 [1024,K] K-major -> NT GEMM, fp16 MFMA.
// Tile 128(M)x128(N), BK=64. 4 waves 2x2; wave tile 64x64 = 4x4 frags 16x16.
// A-frag (16x32): lane holds row lane&15, k=(lane>>4)*8..+7 (contiguous 16B).
// B-frag: col lane&15, same k slice -> W[n][k] contiguous. C: col=lane&15,
// row=(lane>>4)*4+reg.
__global__ __launch_bounds__(256, 2) void proj_mfma(
    const float* __restrict__ A, int K,
    const float* __restrict__ Wf, const float* __restrict__ Wr,
    const float* __restrict__ bih_f, const float* __restrict__ bhh_f,
    const float* __restrict__ bih_r, const float* __restrict__ bhh_r,
    __half* __restrict__ xg)
{
    const int dir = blockIdx.z;
    const float* __restrict__ W   = dir ? Wr    : Wf;
    const float* __restrict__ bih = dir ? bih_r : bih_f;
    const float* __restrict__ bhh = dir ? bhh_r : bhh_f;
    __half* __restrict__ outp = xg + (size_t)dir * ((size_t)BATCH * T_LEN * G4);

    // As/Bs: [128][72] halves (pad 64->72 breaks bank alignment). Cs overlays.
    __shared__ char psm[36864];
    __half* As = (__half*)psm;                // [128][72]
    __half* Bs = (__half*)(psm + 18432);      // [128][72]

    const int tid  = threadIdx.x;
    const int lane = tid & 63;
    const int wave = tid >> 6;
    const int wm   = wave >> 1;               // wave row 0/1
    const int wn   = wave & 1;                // wave col 0/1
    const int fr   = lane & 15;
    const int fk   = lane >> 4;               // k-chunk 0..3
    const int m0   = blockIdx.y * 128;
    const int n0   = blockIdx.x * 128;

    // per-lane bias for the 4 n-fragments
    float biasv[4];
    #pragma unroll
    for (int ni = 0; ni < 4; ++ni) {
        int n = n0 + wn * 64 + ni * 16 + fr;
        biasv[ni] = bih[n] + bhh[n];
    }

    f32x4 acc[4][4];
    #pragma unroll
    for (int mi = 0; mi < 4; ++mi)
        #pragma unroll
        for (int ni = 0; ni < 4; ++ni)
            acc[mi][ni] = (f32x4){0.f, 0.f, 0.f, 0.f};

    for (int k0 = 0; k0 < K; k0 += 64) {
        // stage A,B tiles: f32 -> f16, 128 rows x 64 k each
        #pragma unroll
        for (int it = 0; it < 4; ++it) {
            int t2  = tid + it * 256;
            int row = t2 >> 3;
            int ks  = (t2 & 7) * 8;
            const float* pa = &A[(size_t)(m0 + row) * K + k0 + ks];
            const float* pb = &W[(size_t)(n0 + row) * K + k0 + ks];
            float4 a0 = *reinterpret_cast<const float4*>(pa);
            float4 a1 = *reinterpret_cast<const float4*>(pa + 4);
            float4 b0 = *reinterpret_cast<const float4*>(pb);
            float4 b1 = *reinterpret_cast<const float4*>(pb + 4);
            Half8 ha, hb;
            ha.h[0] = __float2half(a0.x); ha.h[1] = __float2half(a0.y);
            ha.h[2] = __float2half(a0.z); ha.h[3] = __float2half(a0.w);
            ha.h[4] = __float2half(a1.x); ha.h[5] = __float2half(a1.y);
            ha.h[6] = __float2half(a1.z); ha.h[7] = __float2half(a1.w);
            hb.h[0] = __float2half(b0.x); hb.h[1] = __float2half(b0.y);
            hb.h[2] = __float2half(b0.z); hb.h[3] = __float2half(b0.w);
            hb.h[4] = __float2half(b1.x); hb.h[5] = __float2half(b1.y);
            hb.h[6] = __float2half(b1.z); hb.h[7] = __float2half(b1.w);
            *reinterpret_cast<Half8*>(&As[row * 72 + ks]) = ha;
            *reinterpret_cast<Half8*>(&Bs[row * 72 + ks]) = hb;
        }
        __syncthreads();

        #pragma unroll
        for (int kk = 0; kk < 2; ++kk) {      // k sub-slices 0..31, 32..63
            half8_t af[4], bf[4];
            #pragma unroll
            for (int mi = 0; mi < 4; ++mi)
                af[mi] = *reinterpret_cast<const half8_t*>(
                    &As[(wm * 64 + mi * 16 + fr) * 72 + kk * 32 + fk * 8]);
            #pragma unroll
            for (int ni = 0; ni < 4; ++ni)
                bf[ni] = *reinterpret_cast<const half8_t*>(
                    &Bs[(wn * 64 + ni * 16 + fr) * 72 + kk * 32 + fk * 8]);
            #pragma unroll
            for (int mi = 0; mi < 4; ++mi)
                #pragma unroll
                for (int ni = 0; ni < 4; ++ni)
                    acc[mi][ni] = __builtin_amdgcn_mfma_f32_16x16x32_f16(
                        af[mi], bf[ni], acc[mi][ni], 0, 0, 0);
        }
        __syncthreads();
    }

    // epilogue: bias + f16 via Cs [128][136] (rows 272B, 16B-aligned), then
    // fully-coalesced 16B global writes
    __half* Cs = (__half*)psm;
    #pragma unroll
    for (int mi = 0; mi < 4; ++mi)
        #pragma unroll
        for (int ni = 0; ni < 4; ++ni) {
            #pragma unroll
            for (int i = 0; i < 4; ++i) {
                int row = wm * 64 + mi * 16 + fk * 4 + i;
                int col = wn * 64 + ni * 16 + fr;
                Cs[row * 136 + col] = __float2half(acc[mi][ni][i] + biasv[ni]);
            }
        }
    __syncthreads();
    #pragma unroll
    for (int it = 0; it < 8; ++it) {
        int slot = it * 256 + tid;
        int row  = slot >> 4;
        int c8   = (slot & 15) * 8;
        Half8 v = *reinterpret_cast<const Half8*>(&Cs[row * 136 + c8]);
        *reinterpret_cast<Half8*>(&outp[(size_t)(m0 + row) * G4 + n0 + c8]) = v;
    }
}

// ---- cooperative recurrence: group-of-4, same-XCD, 512-thread wgs (r11) ----
// bid = jq*64 + (d*32 + b): jq = bid>>6, d = (bid>>5)&1, b = bid&31.
// All 4 jq of one (d,b) share bid%8 -> same XCD (perf heuristic only).
// thread: kh = tid>>8 (k-half), r = tid&255 (local row). Gate row
// n = (r>>6)*256 + jq*64 + (r&63). W = n's k-half = 128 fp16 = 64 VGPRs.
// Epilogue: tid<64 -> h_j, j = jq*64 + tid. Pollers: tid in [256,448).
extern "C" __global__ __launch_bounds__(512, 2) void recur10_kernel(
    const __half* __restrict__ xg,
    const float* __restrict__ Whh_f,           // [1024][256]
    const float* __restrict__ Whh_r,
    float* __restrict__ outp,                  // [32][1024][512]
    unsigned long long* __restrict__ hbt,      // [2][32][2][256] tagged
    unsigned int tagbase)
{
    // 54 KB static LDS: used = hl 1 KB + scr 2 KB; the pad caps occupancy at
    // 2 blocks/CU (3*54KB > 160KB) so the allocator's budget is 128 VGPRs.
    __shared__ char smem[55296];
    __half* hl  = (__half*)smem;            // [2 parity][256 j]
    float*  scr = (float*)(smem + 1024);    // [2 kh][256 r]

    const int tid = threadIdx.x;
    const int bid = blockIdx.x;
    const int jq  = bid >> 6;
    const int d   = (bid >> 5) & 1;
    const int b   = bid & 31;
    const float* __restrict__ Whh = d ? Whh_r : Whh_f;

    const int kh = tid >> 8;                  // k-half 0/1 (wave-uniform)
    const int r  = tid & 255;                 // local row
    const int q  = r >> 6;                    // gate 0..3
    const int jl = r & 63;
    const int n_my = (q << 8) + jq * 64 + jl; // global gate row

    // --- one-time: 128 fp16 weights (row n_my, k-half kh) = 64 half2 VGPRs ---
    unsigned wh[64];
    {
        const float* wrow = Whh + (size_t)n_my * HID + kh * 128;
        #pragma unroll
        for (int i = 0; i < 32; ++i) {
            float4 w4 = *reinterpret_cast<const float4*>(&wrow[i * 4]);
            wh[2 * i]     = __builtin_bit_cast(unsigned, pack_f16x2(w4.x, w4.y));
            wh[2 * i + 1] = __builtin_bit_cast(unsigned, pack_f16x2(w4.z, w4.w));
        }
    }
    #pragma unroll
    for (int i = 0; i < 64; ++i) asm volatile("" : "+v"(wh[i]));   // no remat

    unsigned long long* hb = hbt + (size_t)(d * 32 + b) * 512;   // [parity][256]

    // init: h[-1]=0 -> global tag (peers) + local LDS parity-0 own quarter
    if (tid < 64) {
        __hip_atomic_store(&hb[256 + jq * 64 + tid],
                           (unsigned long long)tagbase << 32,
                           __ATOMIC_RELAXED, __HIP_MEMORY_SCOPE_AGENT);
        hl[0 * 256 + jq * 64 + tid] = __float2half(0.f);
    }

    // poller role: tids [256,448) each own ONE foreign slot
    const bool isPoll = (tid >= 256) && (tid < 448);
    int pslot = 0;
    if (isPoll) {
        int u  = tid - 256;            // 0..191
        int fq = u >> 6;               // 0..2
        int qq = fq + (fq >= jq);      // skip own quarter
        pslot  = qq * 64 + (u & 63);
    }

    // xg: kh==0 threads add xg(b, n_my)
    const __half* __restrict__ xgp =
        xg + ((size_t)(d * BATCH + b)) * T_LEN * G4 + n_my;

    float c_state = 0.f;               // tid<64: cell j = jq*64 + tid

    for (int st = 0; st < T_LEN; ++st) {
        const int t = d ? (T_LEN - 1 - st) : st;

        // prefetch xg (independent of h) before polling
        float xv = (kh == 0) ? __half2float(xgp[(size_t)t * G4]) : 0.f;

        __half* hlcur = hl + (st & 1) * 256;

        // stage foreign quarters (parity (st+1)&1, tag tagbase+st); own quarter
        // was written locally by epilogue at st-1 (or init)
        if (isPoll) {
            const unsigned int exp = tagbase + (unsigned)st;
            unsigned long long* src = hb + (size_t)((st + 1) & 1) * 256 + pslot;
            unsigned long long v =
                __hip_atomic_load(src, __ATOMIC_RELAXED, __HIP_MEMORY_SCOPE_AGENT);
            while ((unsigned int)(v >> 32) != exp)
                v = __hip_atomic_load(src, __ATOMIC_RELAXED, __HIP_MEMORY_SCOPE_AGENT);
            hlcur[pslot] = __float2half(__uint_as_float((unsigned int)v));
        }
        __syncthreads();   // hl[st&1] complete

        // 128-k dot: W in 64 half2 VGPRs, h via broadcast ds_read_b128
        float a0 = xv, a1 = 0.f;
        {
            const float4* hp = reinterpret_cast<const float4*>(hlcur + kh * 128);
            #pragma unroll
            for (int i = 0; i < 16; ++i) {
                float4 hv = hp[i];
                a0 = dot2acc(__builtin_bit_cast(f16x2, hv.x), __builtin_bit_cast(f16x2, wh[4 * i + 0]), a0);
                a1 = dot2acc(__builtin_bit_cast(f16x2, hv.y), __builtin_bit_cast(f16x2, wh[4 * i + 1]), a1);
                a0 = dot2acc(__builtin_bit_cast(f16x2, hv.z), __builtin_bit_cast(f16x2, wh[4 * i + 2]), a0);
                a1 = dot2acc(__builtin_bit_cast(f16x2, hv.w), __builtin_bit_cast(f16x2, wh[4 * i + 3]), a1);
            }
        }
        scr[kh * 256 + r] = a0 + a1;
        __syncthreads();

        if (tid < 64) {
            float gi = scr[      tid] + scr[256 +       tid];
            float gf = scr[ 64 + tid] + scr[256 +  64 + tid];
            float gg = scr[128 + tid] + scr[256 + 128 + tid];
            float go = scr[192 + tid] + scr[256 + 192 + tid];
            float ii = sigm(gi);
            float ff = sigm(gf);
            float g2 = tanh_fast(gg);
            float oo = sigm(go);
            c_state = ff * c_state + ii * g2;
            float h = oo * tanh_fast(c_state);
            const int j = jq * 64 + tid;
            // local fast path for own wg (read at st+1 from hl[(st+1)&1])
            hl[((st + 1) & 1) * 256 + j] = __float2half(h);
            // global tagged store for the 3 same-XCD peers
            unsigned long long pv =
                ((unsigned long long)(tagbase + (unsigned)st + 1u) << 32) | __float_as_uint(h);
            __hip_atomic_store(&hb[(size_t)(st & 1) * 256 + j], pv,
                               __ATOMIC_RELAXED, __HIP_MEMORY_SCOPE_AGENT);
            outp[((size_t)b * T_LEN + t) * (2 * HID) + d * HID + j] = h;
        }
        // no 3rd barrier: next step's post-stage barrier orders scr reuse; the
        // epilogue's hl[(st+1)&1] writes are to slots disjoint from pollers'.
    }
}

extern "C" void kernel_launch(void* const* d_in, const int* in_sizes, int n_in,
                              void* d_out, int out_size, void* d_ws, size_t ws_size,
                              hipStream_t stream)
{
    const float* x       = (const float*)d_in[0];
    const float* W_ih_f0 = (const float*)d_in[1];
    const float* W_hh_f0 = (const float*)d_in[2];
    const float* b_ih_f0 = (const float*)d_in[3];
    const float* b_hh_f0 = (const float*)d_in[4];
    const float* W_ih_r0 = (const float*)d_in[5];
    const float* W_hh_r0 = (const float*)d_in[6];
    const float* b_ih_r0 = (const float*)d_in[7];
    const float* b_hh_r0 = (const float*)d_in[8];
    const float* W_ih_f1 = (const float*)d_in[9];
    const float* W_hh_f1 = (const float*)d_in[10];
    const float* b_ih_f1 = (const float*)d_in[11];
    const float* b_hh_f1 = (const float*)d_in[12];
    const float* W_ih_r1 = (const float*)d_in[13];
    const float* W_hh_r1 = (const float*)d_in[14];
    const float* b_ih_r1 = (const float*)d_in[15];
    const float* b_hh_r1 = (const float*)d_in[16];

    float* outp = (float*)d_out;

    __half* xg = (__half*)d_ws;
    const size_t xg_bytes = (size_t)2 * BATCH * T_LEN * G4 * sizeof(__half); // 134,217,728
    unsigned long long* hbt = (unsigned long long*)((char*)d_ws + xg_bytes); // 262,144 B

    // clean tag space every launch (no stale-tag pre-match, fully replay-safe)
    hipMemsetAsync(hbt, 0, 262144, stream);

    // ---- layer 0 ----
    proj_mfma<<<dim3(8, 256, 2), 256, 0, stream>>>(x, 256, W_ih_f0, W_ih_r0,
        b_ih_f0, b_hh_f0, b_ih_r0, b_hh_r0, xg);
    {
        const __half* xg_c = xg;
        unsigned int base0 = 1u;
        void* args[] = {(void*)&xg_c, (void*)&W_hh_f0, (void*)&W_hh_r0,
                        (void*)&outp, (void*)&hbt, (void*)&base0};
        hipLaunchCooperativeKernel(reinterpret_cast<const void*>(recur10_kernel),
                                   dim3(256), dim3(512), args, 0, stream);
    }

    // ---- layer 1 ----
    proj_mfma<<<dim3(8, 256, 2), 256, 0, stream>>>(outp, 512, W_ih_f1, W_ih_r1,
        b_ih_f1, b_hh_f1, b_ih_r1, b_hh_r1, xg);
    {
        const __half* xg_c = xg;
        unsigned int base1 = 4096u;
        void* args[] = {(void*)&xg_c, (void*)&W_hh_f1, (void*)&W_hh_r1,
                        (void*)&outp, (void*)&hbt, (void*)&base1};
        hipLaunchCooperativeKernel(reinterpret_cast<const void*>(recur10_kernel),
                                   dim3(256), dim3(512), args, 0, stream);
    }
}

// Round 14
// 2923.276 us; speedup vs baseline: 1.3780x; 1.0236x over previous
//
#include <hip/hip_runtime.h>
#include <hip/hip_fp16.h>

// Bidirectional 2-layer LSTM: B=32, T=1024, IN=256, H=256.
// ws layout: xg  f16 [2][32][1024][1024]        = 134,217,728 B
//            hbt u64 [2][32][2 parity][256]     =     262,144 B (pair-tagged h)
// total = 134,479,872 B
//
// Tag protocol (per layer, base B): producer at step st stores (B+st+1, pair)
// into parity st&1; consumer at step st polls parity (st+1)&1 for tag B+st.
// L0 base=1, L1 base=4096; hbt memset to 0 each launch (replay-safe).
// r14: pair-packed exchange — one u64 = tag32 | (h_{2p+1} fp16 <<16 | h_{2p}).
// Halves tagged WRITE (134->67MB) and poll count (192->96/wg). Pairing done
// with one quad_perm DPP in the 64-lane epilogue wave (VALU, no LDS pipe —
// r12's ds_swizzle lesson). All else identical to r13 (best: 2992us).

#define T_LEN 1024
#define BATCH 32
#define HID   256
#define G4    1024

struct __align__(16) Half8 { __half h[8]; };

typedef _Float16 f16x2 __attribute__((ext_vector_type(2)));
typedef _Float16 half8_t __attribute__((ext_vector_type(8)));
typedef float f32x4 __attribute__((ext_vector_type(4)));

__device__ __forceinline__ f16x2 pack_f16x2(float lo, float hi) {
    f16x2 r; r.x = (_Float16)lo; r.y = (_Float16)hi; return r;
}
__device__ __forceinline__ float dot2acc(f16x2 a, f16x2 b, float c) {
#if __has_builtin(__builtin_amdgcn_fdot2)
    return __builtin_amdgcn_fdot2(a, b, c, false);
#else
    return c + (float)a.x * (float)b.x + (float)a.y * (float)b.y;
#endif
}

template <int CTRL>
__device__ __forceinline__ unsigned qperm_u32(unsigned v) {
    int r = __builtin_amdgcn_update_dpp((int)v, (int)v, CTRL, 0xF, 0xF, true);
    return (unsigned)r;
}

__device__ __forceinline__ float sigm(float x) { return 1.0f / (1.0f + __expf(-x)); }
__device__ __forceinline__ float tanh_fast(float x) {
    float e = __expf(2.f * x);            // inf-safe
    return 1.f - 2.f / (e + 1.f);
}

// ---- MFMA projection (r13, unchanged): xg = A*W^T + bias, fp16 out ----
__global__ __launch_bounds__(256, 2) void proj_mfma(
    const float* __restrict__ A, int K,
    const float* __restrict__ Wf, const float* __restrict__ Wr,
    const float* __restrict__ bih_f, const float* __restrict__ bhh_f,
    const float* __restrict__ bih_r, const float* __restrict__ bhh_r,
    __half* __restrict__ xg)
{
    const int dir = blockIdx.z;
    const float* __restrict__ W   = dir ? Wr    : Wf;
    const float* __restrict__ bih = dir ? bih_r : bih_f;
    const float* __restrict__ bhh = dir ? bhh_r : bhh_f;
    __half* __restrict__ outp = xg + (size_t)dir * ((size_t)BATCH * T_LEN * G4);

    __shared__ char psm[36864];
    __half* As = (__half*)psm;                // [128][72]
    __half* Bs = (__half*)(psm + 18432);      // [128][72]

    const int tid  = threadIdx.x;
    const int lane = tid & 63;
    const int wave = tid >> 6;
    const int wm   = wave >> 1;
    const int wn   = wave & 1;
    const int fr   = lane & 15;
    const int fk   = lane >> 4;
    const int m0   = blockIdx.y * 128;
    const int n0   = blockIdx.x * 128;

    float biasv[4];
    #pragma unroll
    for (int ni = 0; ni < 4; ++ni) {
        int n = n0 + wn * 64 + ni * 16 + fr;
        biasv[ni] = bih[n] + bhh[n];
    }

    f32x4 acc[4][4];
    #pragma unroll
    for (int mi = 0; mi < 4; ++mi)
        #pragma unroll
        for (int ni = 0; ni < 4; ++ni)
            acc[mi][ni] = (f32x4){0.f, 0.f, 0.f, 0.f};

    for (int k0 = 0; k0 < K; k0 += 64) {
        #pragma unroll
        for (int it = 0; it < 4; ++it) {
            int t2  = tid + it * 256;
            int row = t2 >> 3;
            int ks  = (t2 & 7) * 8;
            const float* pa = &A[(size_t)(m0 + row) * K + k0 + ks];
            const float* pb = &W[(size_t)(n0 + row) * K + k0 + ks];
            float4 a0 = *reinterpret_cast<const float4*>(pa);
            float4 a1 = *reinterpret_cast<const float4*>(pa + 4);
            float4 b0 = *reinterpret_cast<const float4*>(pb);
            float4 b1 = *reinterpret_cast<const float4*>(pb + 4);
            Half8 ha, hb;
            ha.h[0] = __float2half(a0.x); ha.h[1] = __float2half(a0.y);
            ha.h[2] = __float2half(a0.z); ha.h[3] = __float2half(a0.w);
            ha.h[4] = __float2half(a1.x); ha.h[5] = __float2half(a1.y);
            ha.h[6] = __float2half(a1.z); ha.h[7] = __float2half(a1.w);
            hb.h[0] = __float2half(b0.x); hb.h[1] = __float2half(b0.y);
            hb.h[2] = __float2half(b0.z); hb.h[3] = __float2half(b0.w);
            hb.h[4] = __float2half(b1.x); hb.h[5] = __float2half(b1.y);
            hb.h[6] = __float2half(b1.z); hb.h[7] = __float2half(b1.w);
            *reinterpret_cast<Half8*>(&As[row * 72 + ks]) = ha;
            *reinterpret_cast<Half8*>(&Bs[row * 72 + ks]) = hb;
        }
        __syncthreads();

        #pragma unroll
        for (int kk = 0; kk < 2; ++kk) {
            half8_t af[4], bf[4];
            #pragma unroll
            for (int mi = 0; mi < 4; ++mi)
                af[mi] = *reinterpret_cast<const half8_t*>(
                    &As[(wm * 64 + mi * 16 + fr) * 72 + kk * 32 + fk * 8]);
            #pragma unroll
            for (int ni = 0; ni < 4; ++ni)
                bf[ni] = *reinterpret_cast<const half8_t*>(
                    &Bs[(wn * 64 + ni * 16 + fr) * 72 + kk * 32 + fk * 8]);
            #pragma unroll
            for (int mi = 0; mi < 4; ++mi)
                #pragma unroll
                for (int ni = 0; ni < 4; ++ni)
                    acc[mi][ni] = __builtin_amdgcn_mfma_f32_16x16x32_f16(
                        af[mi], bf[ni], acc[mi][ni], 0, 0, 0);
        }
        __syncthreads();
    }

    __half* Cs = (__half*)psm;
    #pragma unroll
    for (int mi = 0; mi < 4; ++mi)
        #pragma unroll
        for (int ni = 0; ni < 4; ++ni) {
            #pragma unroll
            for (int i = 0; i < 4; ++i) {
                int row = wm * 64 + mi * 16 + fk * 4 + i;
                int col = wn * 64 + ni * 16 + fr;
                Cs[row * 136 + col] = __float2half(acc[mi][ni][i] + biasv[ni]);
            }
        }
    __syncthreads();
    #pragma unroll
    for (int it = 0; it < 8; ++it) {
        int slot = it * 256 + tid;
        int row  = slot >> 4;
        int c8   = (slot & 15) * 8;
        Half8 v = *reinterpret_cast<const Half8*>(&Cs[row * 136 + c8]);
        *reinterpret_cast<Half8*>(&outp[(size_t)(m0 + row) * G4 + n0 + c8]) = v;
    }
}

// ---- cooperative recurrence: r13 structure + pair-packed exchange ----
// bid = jq*64 + (d*32 + b): jq = bid>>6, d = (bid>>5)&1, b = bid&31.
// thread: kh = tid>>8, r = tid&255. Gate row n = (r>>6)*256 + jq*64 + (r&63).
// W = n's k-half = 128 fp16 = 64 VGPRs. Epilogue: tid<64 (wave 0).
// Pollers: tid in [256,352) -> 96, one u64 pair-slot each.
extern "C" __global__ __launch_bounds__(512, 2) void recur12_kernel(
    const __half* __restrict__ xg,
    const float* __restrict__ Whh_f,           // [1024][256]
    const float* __restrict__ Whh_r,
    float* __restrict__ outp,                  // [32][1024][512]
    unsigned long long* __restrict__ hbt,      // [2][32][2][256] (128 used/parity)
    unsigned int tagbase)
{
    // 54 KB static LDS pad: caps occupancy at 2 blocks/CU -> VGPR budget 128.
    __shared__ char smem[55296];
    __half* hl  = (__half*)smem;            // [2 parity][256 j]
    float*  scr = (float*)(smem + 1024);    // [2 kh][256 r]

    const int tid = threadIdx.x;
    const int bid = blockIdx.x;
    const int jq  = bid >> 6;
    const int d   = (bid >> 5) & 1;
    const int b   = bid & 31;
    const float* __restrict__ Whh = d ? Whh_r : Whh_f;

    const int kh = tid >> 8;
    const int r  = tid & 255;
    const int q  = r >> 6;
    const int jl = r & 63;
    const int n_my = (q << 8) + jq * 64 + jl;

    // --- one-time: 128 fp16 weights (row n_my, k-half kh) = 64 half2 VGPRs ---
    unsigned wh[64];
    {
        const float* wrow = Whh + (size_t)n_my * HID + kh * 128;
        #pragma unroll
        for (int i = 0; i < 32; ++i) {
            float4 w4 = *reinterpret_cast<const float4*>(&wrow[i * 4]);
            wh[2 * i]     = __builtin_bit_cast(unsigned, pack_f16x2(w4.x, w4.y));
            wh[2 * i + 1] = __builtin_bit_cast(unsigned, pack_f16x2(w4.z, w4.w));
        }
    }
    #pragma unroll
    for (int i = 0; i < 64; ++i) asm volatile("" : "+v"(wh[i]));   // no remat

    unsigned long long* hb = hbt + (size_t)(d * 32 + b) * 512;   // [parity][256]

    // init: h[-1]=0 -> parity-1 pair tags (32 slots) + local stage parity-0
    if (tid < 32) {
        __hip_atomic_store(&hb[256 + jq * 32 + tid],
                           (unsigned long long)tagbase << 32,
                           __ATOMIC_RELAXED, __HIP_MEMORY_SCOPE_AGENT);
    }
    if (tid < 64) hl[0 * 256 + jq * 64 + tid] = __float2half(0.f);

    // poller role: tids [256,352) each own ONE foreign pair-slot
    const bool isPoll = (tid >= 256) && (tid < 352);
    int pslot = 0, pdst = 0;
    if (isPoll) {
        int u  = tid - 256;            // 0..95
        int fq = u >> 5;               // 0..2
        int qq = fq + (fq >= jq);      // skip own quarter
        int pi = u & 31;
        pslot  = qq * 32 + pi;
        pdst   = qq * 64 + pi * 2;     // __half index (even)
    }

    // xg: kh==0 threads add xg(b, n_my)
    const __half* __restrict__ xgp =
        xg + ((size_t)(d * BATCH + b)) * T_LEN * G4 + n_my;

    float c_state = 0.f;               // tid<64: cell j = jq*64 + tid

    for (int st = 0; st < T_LEN; ++st) {
        const int t = d ? (T_LEN - 1 - st) : st;

        // prefetch xg (independent of h) before polling
        float xv = (kh == 0) ? __half2float(xgp[(size_t)t * G4]) : 0.f;

        __half* hlcur = hl + (st & 1) * 256;

        // stage foreign quarters (parity (st+1)&1, tag tagbase+st)
        if (isPoll) {
            const unsigned int exp = tagbase + (unsigned)st;
            unsigned long long* src = hb + (size_t)((st + 1) & 1) * 256 + pslot;
            unsigned long long v =
                __hip_atomic_load(src, __ATOMIC_RELAXED, __HIP_MEMORY_SCOPE_AGENT);
            while ((unsigned int)(v >> 32) != exp)
                v = __hip_atomic_load(src, __ATOMIC_RELAXED, __HIP_MEMORY_SCOPE_AGENT);
            *reinterpret_cast<unsigned*>(&hlcur[pdst]) = (unsigned)v;   // 2 fp16
        }
        __syncthreads();   // hl[st&1] complete

        // 128-k dot: W in 64 half2 VGPRs, h via broadcast ds_read_b128
        float a0 = xv, a1 = 0.f;
        {
            const float4* hp = reinterpret_cast<const float4*>(hlcur + kh * 128);
            #pragma unroll
            for (int i = 0; i < 16; ++i) {
                float4 hv = hp[i];
                a0 = dot2acc(__builtin_bit_cast(f16x2, hv.x), __builtin_bit_cast(f16x2, wh[4 * i + 0]), a0);
                a1 = dot2acc(__builtin_bit_cast(f16x2, hv.y), __builtin_bit_cast(f16x2, wh[4 * i + 1]), a1);
                a0 = dot2acc(__builtin_bit_cast(f16x2, hv.z), __builtin_bit_cast(f16x2, wh[4 * i + 2]), a0);
                a1 = dot2acc(__builtin_bit_cast(f16x2, hv.w), __builtin_bit_cast(f16x2, wh[4 * i + 3]), a1);
            }
        }
        scr[kh * 256 + r] = a0 + a1;
        __syncthreads();

        if (tid < 64) {   // epilogue = wave 0 exactly
            float gi = scr[      tid] + scr[256 +       tid];
            float gf = scr[ 64 + tid] + scr[256 +  64 + tid];
            float gg = scr[128 + tid] + scr[256 + 128 + tid];
            float go = scr[192 + tid] + scr[256 + 192 + tid];
            float ii = sigm(gi);
            float ff = sigm(gf);
            float g2 = tanh_fast(gg);
            float oo = sigm(go);
            c_state = ff * c_state + ii * g2;
            float h = oo * tanh_fast(c_state);
            const int j = jq * 64 + tid;

            // local fast path (read at st+1 from hl[(st+1)&1])
            __half h16 = __float2half(h);
            hl[((st + 1) & 1) * 256 + j] = h16;

            // pair-pack via quad_perm (lane^1 neighbor), even lanes store
            unsigned hbits = (unsigned)__builtin_bit_cast(unsigned short, h16);
            unsigned nb = qperm_u32<0xB1>(hbits);      // lane j <- h of j^1
            if ((tid & 1) == 0) {
                unsigned payload = hbits | (nb << 16); // cells 2p (lo), 2p+1 (hi)
                unsigned long long pv =
                    ((unsigned long long)(tagbase + (unsigned)st + 1u) << 32) | payload;
                __hip_atomic_store(&hb[(size_t)(st & 1) * 256 + jq * 32 + (tid >> 1)], pv,
                                   __ATOMIC_RELAXED, __HIP_MEMORY_SCOPE_AGENT);
            }
            outp[((size_t)b * T_LEN + t) * (2 * HID) + d * HID + j] = h;
        }
        // no 3rd barrier: next step's post-stage barrier orders scr reuse; the
        // epilogue's hl[(st+1)&1] writes are to slots disjoint from pollers'.
    }
}

extern "C" void kernel_launch(void* const* d_in, const int* in_sizes, int n_in,
                              void* d_out, int out_size, void* d_ws, size_t ws_size,
                              hipStream_t stream)
{
    const float* x       = (const float*)d_in[0];
    const float* W_ih_f0 = (const float*)d_in[1];
    const float* W_hh_f0 = (const float*)d_in[2];
    const float* b_ih_f0 = (const float*)d_in[3];
    const float* b_hh_f0 = (const float*)d_in[4];
    const float* W_ih_r0 = (const float*)d_in[5];
    const float* W_hh_r0 = (const float*)d_in[6];
    const float* b_ih_r0 = (const float*)d_in[7];
    const float* b_hh_r0 = (const float*)d_in[8];
    const float* W_ih_f1 = (const float*)d_in[9];
    const float* W_hh_f1 = (const float*)d_in[10];
    const float* b_ih_f1 = (const float*)d_in[11];
    const float* b_hh_f1 = (const float*)d_in[12];
    const float* W_ih_r1 = (const float*)d_in[13];
    const float* W_hh_r1 = (const float*)d_in[14];
    const float* b_ih_r1 = (const float*)d_in[15];
    const float* b_hh_r1 = (const float*)d_in[16];

    float* outp = (float*)d_out;

    __half* xg = (__half*)d_ws;
    const size_t xg_bytes = (size_t)2 * BATCH * T_LEN * G4 * sizeof(__half); // 134,217,728
    unsigned long long* hbt = (unsigned long long*)((char*)d_ws + xg_bytes); // 262,144 B

    // clean tag space every launch (no stale-tag pre-match, fully replay-safe)
    hipMemsetAsync(hbt, 0, 262144, stream);

    // ---- layer 0 ----
    proj_mfma<<<dim3(8, 256, 2), 256, 0, stream>>>(x, 256, W_ih_f0, W_ih_r0,
        b_ih_f0, b_hh_f0, b_ih_r0, b_hh_r0, xg);
    {
        const __half* xg_c = xg;
        unsigned int base0 = 1u;
        void* args[] = {(void*)&xg_c, (void*)&W_hh_f0, (void*)&W_hh_r0,
                        (void*)&outp, (void*)&hbt, (void*)&base0};
        hipLaunchCooperativeKernel(reinterpret_cast<const void*>(recur12_kernel),
                                   dim3(256), dim3(512), args, 0, stream);
    }

    // ---- layer 1 ----
    proj_mfma<<<dim3(8, 256, 2), 256, 0, stream>>>(outp, 512, W_ih_f1, W_ih_r1,
        b_ih_f1, b_hh_f1, b_ih_r1, b_hh_r1, xg);
    {
        const __half* xg_c = xg;
        unsigned int base1 = 4096u;
        void* args[] = {(void*)&xg_c, (void*)&W_hh_f1, (void*)&W_hh_r1,
                        (void*)&outp, (void*)&hbt, (void*)&base1};
        hipLaunchCooperativeKernel(reinterpret_cast<const void*>(recur12_kernel),
                                   dim3(256), dim3(512), args, 0, stream);
    }
}